// Round 3
// baseline (1196.036 us; speedup 1.0000x reference)
//
#include <hip/hip_runtime.h>

#define NUMH 16
#define HD   64
#define SEQ  2048
#define NB   2
#define DIM  1024

typedef __attribute__((ext_vector_type(8))) short short8;   // 8 bf16 = 4 VGPR (guide-verified frag type)
typedef __attribute__((ext_vector_type(4))) float f32x4;    // MFMA accumulator

__device__ inline unsigned short bf16_rn(float f) {
    unsigned u = __float_as_uint(f);
    return (unsigned short)((u + 0x7FFFu + ((u >> 16) & 1u)) >> 16);
}
__device__ inline float bf16_to_f(unsigned short h) {
    return __uint_as_float(((unsigned)h) << 16);
}

// ---------------------------------------------------------------------------
// GEMM: out = A[M,K] @ W[K,N] + bias[N]   (fp32 VALU path — audited baseline)
// MODE 0: row-major [M,N] write. MODE 1: scatter into [B,H,S,Hd].
// ---------------------------------------------------------------------------
template<int MODE>
__global__ __launch_bounds__(256, 2)
void gemm128x64(const float* __restrict__ A, const float* __restrict__ W,
                const float* __restrict__ bias, float* __restrict__ out,
                int M, int N, int K)
{
    __shared__ float As[16][132];   // As[k][row], transposed A tile
    __shared__ float Bs[16][64];    // Bs[k][col]

    const int tid = threadIdx.x;
    const int tx  = tid & 15;
    const int ty  = tid >> 4;
    const int m0  = blockIdx.x * 128;
    const int n0  = blockIdx.y * 64;

    float acc[2][4][4];
#pragma unroll
    for (int p = 0; p < 2; ++p)
#pragma unroll
        for (int i = 0; i < 4; ++i)
#pragma unroll
            for (int j = 0; j < 4; ++j) acc[p][i][j] = 0.f;

    const int arow = tid >> 2;
    const int ak   = (tid & 3) * 4;
    const int bk   = tid >> 4;
    const int bn   = (tid & 15) * 4;

    for (int kt = 0; kt < K; kt += 16) {
        __syncthreads();
#pragma unroll
        for (int p = 0; p < 2; ++p) {
            const float4 av = *(const float4*)&A[(size_t)(m0 + arow + p * 64) * K + kt + ak];
            As[ak + 0][arow + p * 64] = av.x;
            As[ak + 1][arow + p * 64] = av.y;
            As[ak + 2][arow + p * 64] = av.z;
            As[ak + 3][arow + p * 64] = av.w;
        }
        *(float4*)&Bs[bk][bn] = *(const float4*)&W[(size_t)(kt + bk) * N + n0 + bn];
        __syncthreads();

#pragma unroll
        for (int k = 0; k < 16; ++k) {
            const float4 a0 = *(const float4*)&As[k][ty * 4];
            const float4 a1 = *(const float4*)&As[k][ty * 4 + 64];
            const float4 b0 = *(const float4*)&Bs[k][tx * 4];
            const float a[2][4] = {{a0.x, a0.y, a0.z, a0.w}, {a1.x, a1.y, a1.z, a1.w}};
            const float b[4]    = {b0.x, b0.y, b0.z, b0.w};
#pragma unroll
            for (int p = 0; p < 2; ++p)
#pragma unroll
                for (int i = 0; i < 4; ++i)
#pragma unroll
                    for (int j = 0; j < 4; ++j)
                        acc[p][i][j] = fmaf(a[p][i], b[j], acc[p][i][j]);
        }
    }

    const int c = n0 + tx * 4;
    const float4 bv = *(const float4*)&bias[c];
#pragma unroll
    for (int p = 0; p < 2; ++p)
#pragma unroll
        for (int i = 0; i < 4; ++i) {
            const int r = m0 + p * 64 + ty * 4 + i;
            float4 o;
            o.x = acc[p][i][0] + bv.x;
            o.y = acc[p][i][1] + bv.y;
            o.z = acc[p][i][2] + bv.z;
            o.w = acc[p][i][3] + bv.w;
            if (MODE == 0) {
                *(float4*)&out[(size_t)r * N + c] = o;
            } else {
                const int b  = r >> 11;
                const int s  = r & (SEQ - 1);
                const int h  = c >> 6;
                const int hd = c & (HD - 1);
                *(float4*)&out[((size_t)(b * NUMH + h) * SEQ + s) * HD + hd] = o;
            }
        }
}

// ---------------------------------------------------------------------------
// Flash attention (fp32), causal — audited baseline, unchanged.
// ---------------------------------------------------------------------------
__global__ __launch_bounds__(256, 2)
void attn64(const float* __restrict__ Q, const float* __restrict__ K,
            const float* __restrict__ V, float* __restrict__ ctx)
{
    __shared__ float Qs[64][68];
    __shared__ float KVs[64][68];
    __shared__ float Ps[64][68];
    __shared__ float red[16][68];
    __shared__ float m_sm[64], l_sm[64], sc_sm[64];

    const int tid = threadIdx.x;
    const int tx  = tid & 15;
    const int ty  = tid >> 4;
    const int bh  = blockIdx.x >> 5;
    const int qt  = blockIdx.x & 31;
    const int bb  = bh >> 4;
    const int h   = bh & 15;
    const size_t base = (size_t)bh * SEQ * HD;
    const int q0  = qt * 64;

    {
        const int r  = tid >> 4;
        const int dq = (tid & 15) * 4;
#pragma unroll
        for (int p = 0; p < 4; ++p) {
            const float4 v = *(const float4*)&Q[base + (size_t)(q0 + r + p * 16) * HD + dq];
            Qs[dq + 0][r + p * 16] = v.x;
            Qs[dq + 1][r + p * 16] = v.y;
            Qs[dq + 2][r + p * 16] = v.z;
            Qs[dq + 3][r + p * 16] = v.w;
        }
    }
    if (tid < 64) { m_sm[tid] = -1e30f; l_sm[tid] = 0.f; }

    float o[4][4];
#pragma unroll
    for (int i = 0; i < 4; ++i)
#pragma unroll
        for (int j = 0; j < 4; ++j) o[i][j] = 0.f;

    for (int kt = 0; kt <= qt; ++kt) {
        const int k0 = kt * 64;
        __syncthreads();

        {
            const int r  = tid >> 4;
            const int dq = (tid & 15) * 4;
#pragma unroll
            for (int p = 0; p < 4; ++p) {
                const float4 v = *(const float4*)&K[base + (size_t)(k0 + r + p * 16) * HD + dq];
                KVs[dq + 0][r + p * 16] = v.x;
                KVs[dq + 1][r + p * 16] = v.y;
                KVs[dq + 2][r + p * 16] = v.z;
                KVs[dq + 3][r + p * 16] = v.w;
            }
        }
        __syncthreads();

        float s[4][4];
#pragma unroll
        for (int i = 0; i < 4; ++i)
#pragma unroll
            for (int j = 0; j < 4; ++j) s[i][j] = 0.f;
#pragma unroll 8
        for (int d = 0; d < 64; ++d) {
            const float4 a4 = *(const float4*)&Qs[d][ty * 4];
            const float4 b4 = *(const float4*)&KVs[d][tx * 4];
            const float a[4] = {a4.x, a4.y, a4.z, a4.w};
            const float b[4] = {b4.x, b4.y, b4.z, b4.w};
#pragma unroll
            for (int i = 0; i < 4; ++i)
#pragma unroll
                for (int j = 0; j < 4; ++j)
                    s[i][j] = fmaf(a[i], b[j], s[i][j]);
        }

        const bool diag = (kt == qt);
#pragma unroll
        for (int i = 0; i < 4; ++i) {
            float pm = -1e30f;
#pragma unroll
            for (int j = 0; j < 4; ++j) {
                float sv = s[i][j] * 0.125f;
                if (diag && (tx * 4 + j > ty * 4 + i)) sv = -1e30f;
                s[i][j] = sv;
                pm = fmaxf(pm, sv);
            }
            red[tx][ty * 4 + i] = pm;
        }
        __syncthreads();

        float4 vreg[4];
        {
            const int r  = tid >> 4;
            const int dq = (tid & 15) * 4;
#pragma unroll
            for (int p = 0; p < 4; ++p)
                vreg[p] = *(const float4*)&V[base + (size_t)(k0 + r + p * 16) * HD + dq];
        }

        if (tid < 64) {
            float mt = red[0][tid];
#pragma unroll
            for (int t = 1; t < 16; ++t) mt = fmaxf(mt, red[t][tid]);
            const float mo = m_sm[tid];
            const float mn = fmaxf(mo, mt);
            sc_sm[tid] = __expf(mo - mn);
            m_sm[tid]  = mn;
        }
        __syncthreads();

#pragma unroll
        for (int i = 0; i < 4; ++i) {
            const int q = ty * 4 + i;
            const float mn = m_sm[q];
            float rs = 0.f;
#pragma unroll
            for (int j = 0; j < 4; ++j) {
                const float pv = __expf(s[i][j] - mn);
                Ps[tx * 4 + j][q] = pv;
                rs += pv;
            }
            red[tx][q] = rs;
            const float scl = sc_sm[q];
#pragma unroll
            for (int j = 0; j < 4; ++j) o[i][j] *= scl;
        }
        {
            const int r  = tid >> 4;
            const int dq = (tid & 15) * 4;
#pragma unroll
            for (int p = 0; p < 4; ++p)
                *(float4*)&KVs[r + p * 16][dq] = vreg[p];
        }
        __syncthreads();

        if (tid < 64) {
            float ls = 0.f;
#pragma unroll
            for (int t = 0; t < 16; ++t) ls += red[t][tid];
            l_sm[tid] = l_sm[tid] * sc_sm[tid] + ls;
        }

#pragma unroll 8
        for (int k = 0; k < 64; ++k) {
            const float4 a4 = *(const float4*)&Ps[k][ty * 4];
            const float4 b4 = *(const float4*)&KVs[k][tx * 4];
            const float a[4] = {a4.x, a4.y, a4.z, a4.w};
            const float b[4] = {b4.x, b4.y, b4.z, b4.w};
#pragma unroll
            for (int i = 0; i < 4; ++i)
#pragma unroll
                for (int j = 0; j < 4; ++j)
                    o[i][j] = fmaf(a[i], b[j], o[i][j]);
        }
    }
    __syncthreads();

#pragma unroll
    for (int i = 0; i < 4; ++i) {
        const int q = ty * 4 + i;
        const int gq = q0 + q;
        const float inv = 1.f / l_sm[q];
        float4 ov;
        ov.x = o[i][0] * inv;
        ov.y = o[i][1] * inv;
        ov.z = o[i][2] * inv;
        ov.w = o[i][3] * inv;
        *(float4*)&ctx[((size_t)bb * SEQ + gq) * DIM + h * HD + tx * 4] = ov;
    }
}

// ---------------------------------------------------------------------------
// SCRAP EXPERIMENT kernels (output goes to workspace only, never to d_out).
// ---------------------------------------------------------------------------
// fp32 -> bf16 hi/lo split, elementwise (for A = x, layout [M][K] kept).
__global__ void convert_split(const float* __restrict__ in,
                              unsigned short* __restrict__ hi,
                              unsigned short* __restrict__ lo, int n4)
{
    for (int i = blockIdx.x * blockDim.x + threadIdx.x; i < n4;
         i += gridDim.x * blockDim.x) {
        const float4 v = ((const float4*)in)[i];
        ushort4 h, l;
        h.x = bf16_rn(v.x); l.x = bf16_rn(v.x - bf16_to_f(h.x));
        h.y = bf16_rn(v.y); l.y = bf16_rn(v.y - bf16_to_f(h.y));
        h.z = bf16_rn(v.z); l.z = bf16_rn(v.z - bf16_to_f(h.z));
        h.w = bf16_rn(v.w); l.w = bf16_rn(v.w - bf16_to_f(h.w));
        ((ushort4*)hi)[i] = h;
        ((ushort4*)lo)[i] = l;
    }
}

// W [K][N] fp32 -> Wt_hi/Wt_lo [N][K] bf16 (transpose + split), 32x32 tiles.
__global__ __launch_bounds__(256)
void transpose_split(const float* __restrict__ W,
                     unsigned short* __restrict__ th,
                     unsigned short* __restrict__ tl)
{
    __shared__ float Ls[32][33];
    const int tx = threadIdx.x & 31, ty = threadIdx.x >> 5;   // 32 x 8
    const int k0 = blockIdx.x * 32, n0 = blockIdx.y * 32;
#pragma unroll
    for (int i = 0; i < 4; ++i)
        Ls[ty + 8 * i][tx] = W[(size_t)(k0 + ty + 8 * i) * DIM + n0 + tx];
    __syncthreads();
#pragma unroll
    for (int i = 0; i < 4; ++i) {
        const float f = Ls[tx][ty + 8 * i];
        const unsigned short h = bf16_rn(f);
        const unsigned short l = bf16_rn(f - bf16_to_f(h));
        th[(size_t)(n0 + ty + 8 * i) * DIM + k0 + tx] = h;
        tl[(size_t)(n0 + ty + 8 * i) * DIM + k0 + tx] = l;
    }
}

// bf16-split MFMA GEMM: out = (Ah+Al)[M,K] @ (Bh+Bl)^T[N,K]^T + bias, fp32 out.
// 3 MFMA passes: hi*hi + hi*lo + lo*hi (lo*lo dropped, ~2^-18 rel).
// Tile 128x64, 256 thr = 4 waves (2x2), each wave 64x32 = 4x2 16x16 frags.
// K-invariance: A and B fragments both use slot j -> k = (lane>>4)*8 + j; any
// consistent mapping gives the correct dot product (C/D layout is HW-verified).
__global__ __launch_bounds__(256, 2)
void gemm_mfma_split(const unsigned short* __restrict__ Ah,
                     const unsigned short* __restrict__ Al,
                     const unsigned short* __restrict__ Bh,
                     const unsigned short* __restrict__ Bl,
                     const float* __restrict__ bias, float* __restrict__ out,
                     int M, int N, int K)
{
    __shared__ unsigned short As_h[128][32];
    __shared__ unsigned short As_l[128][32];
    __shared__ unsigned short Bs_h[64][32];
    __shared__ unsigned short Bs_l[64][32];

    const int tid  = threadIdx.x;
    const int m0   = blockIdx.x * 128;
    const int n0   = blockIdx.y * 64;
    const int wid  = tid >> 6;
    const int lane = tid & 63;
    const int wr   = wid >> 1;      // 0/1: 64-row half
    const int wc   = wid & 1;       // 0/1: 32-col half
    const int fr   = lane & 15;
    const int fg   = lane >> 4;

    f32x4 acc[4][2];
#pragma unroll
    for (int i = 0; i < 4; ++i)
#pragma unroll
        for (int j = 0; j < 2; ++j) { f32x4 z = {0.f, 0.f, 0.f, 0.f}; acc[i][j] = z; }

    const int row0 = tid >> 2;            // 0..63
    const int k80  = (tid & 3) * 8;       // 0,8,16,24

    for (int kt = 0; kt < K; kt += 32) {
        __syncthreads();
        // stage (coalesced 16B/lane global reads, linear 16B LDS writes)
        *(short8*)&As_h[row0][k80]      = *(const short8*)&Ah[(size_t)(m0 + row0) * K + kt + k80];
        *(short8*)&As_h[row0 + 64][k80] = *(const short8*)&Ah[(size_t)(m0 + row0 + 64) * K + kt + k80];
        *(short8*)&As_l[row0][k80]      = *(const short8*)&Al[(size_t)(m0 + row0) * K + kt + k80];
        *(short8*)&As_l[row0 + 64][k80] = *(const short8*)&Al[(size_t)(m0 + row0 + 64) * K + kt + k80];
        *(short8*)&Bs_h[row0][k80]      = *(const short8*)&Bh[(size_t)(n0 + row0) * K + kt + k80];
        *(short8*)&Bs_l[row0][k80]      = *(const short8*)&Bl[(size_t)(n0 + row0) * K + kt + k80];
        __syncthreads();

        short8 afh[4], afl[4], bfh[2], bfl[2];
#pragma unroll
        for (int i = 0; i < 4; ++i) {
            afh[i] = *(const short8*)&As_h[wr * 64 + i * 16 + fr][fg * 8];
            afl[i] = *(const short8*)&As_l[wr * 64 + i * 16 + fr][fg * 8];
        }
#pragma unroll
        for (int j = 0; j < 2; ++j) {
            bfh[j] = *(const short8*)&Bs_h[wc * 32 + j * 16 + fr][fg * 8];
            bfl[j] = *(const short8*)&Bs_l[wc * 32 + j * 16 + fr][fg * 8];
        }
#pragma unroll
        for (int i = 0; i < 4; ++i)
#pragma unroll
            for (int j = 0; j < 2; ++j) {
                acc[i][j] = __builtin_amdgcn_mfma_f32_16x16x32_bf16(afl[i], bfh[j], acc[i][j], 0, 0, 0);
                acc[i][j] = __builtin_amdgcn_mfma_f32_16x16x32_bf16(afh[i], bfl[j], acc[i][j], 0, 0, 0);
                acc[i][j] = __builtin_amdgcn_mfma_f32_16x16x32_bf16(afh[i], bfh[j], acc[i][j], 0, 0, 0);
            }
    }

    // C/D layout (HW-verified m89/m91): col = lane&15, row = (lane>>4)*4 + reg
#pragma unroll
    for (int i = 0; i < 4; ++i)
#pragma unroll
        for (int j = 0; j < 2; ++j) {
            const int col = n0 + wc * 32 + j * 16 + fr;
            const float bv = bias[col];
#pragma unroll
            for (int r = 0; r < 4; ++r) {
                const int rowg = m0 + wr * 64 + i * 16 + fg * 4 + r;
                out[(size_t)rowg * N + col] = acc[i][j][r] + bv;
            }
        }
}

// ---------------------------------------------------------------------------
extern "C" void kernel_launch(void* const* d_in, const int* in_sizes, int n_in,
                              void* d_out, int out_size, void* d_ws, size_t ws_size,
                              hipStream_t stream)
{
    const float* x  = (const float*)d_in[0];
    const float* Wq = (const float*)d_in[1];
    const float* bq = (const float*)d_in[2];
    const float* Wk = (const float*)d_in[3];
    const float* bk = (const float*)d_in[4];
    const float* Wv = (const float*)d_in[5];
    const float* bv = (const float*)d_in[6];
    const float* Wo = (const float*)d_in[7];
    const float* bo = (const float*)d_in[8];

    float* ws = (float*)d_ws;
    const size_t SZ = (size_t)NB * SEQ * DIM;   // 4M floats = 16 MB
    float* Qb = ws;
    float* Kb = ws + SZ;
    float* Vb = ws + 2 * SZ;
    float* Cb = ws + 3 * SZ;

    const int M = NB * SEQ, N = DIM, K = DIM;
    dim3 blk(256);
    dim3 gg(M / 128, N / 64);

    // ---- real path (audited fp32 baseline) ----
    hipLaunchKernelGGL((gemm128x64<1>), gg, blk, 0, stream, x, Wq, bq, Qb, M, N, K);
    hipLaunchKernelGGL((gemm128x64<1>), gg, blk, 0, stream, x, Wk, bk, Kb, M, N, K);
    hipLaunchKernelGGL((gemm128x64<1>), gg, blk, 0, stream, x, Wv, bv, Vb, M, N, K);

    dim3 ga(NB * NUMH * (SEQ / 64));
    hipLaunchKernelGGL(attn64, ga, blk, 0, stream, Qb, Kb, Vb, Cb);

    hipLaunchKernelGGL((gemm128x64<0>), gg, blk, 0, stream, Cb, Wo, bo, (float*)d_out, M, N, K);

    // ---- scrap experiment: bf16-split MFMA GEMM (x@Wq+bq), ws-only ----
    const size_t MB = 1024 * 1024;
    const size_t need = 100 * MB;   // 64 real + 16(xh,xl) + 4(Wth,Wtl) + 16(scrap)
    if (ws_size >= need) {
        char* base = (char*)d_ws;
        unsigned short* xh   = (unsigned short*)(base + 64 * MB);
        unsigned short* xl   = (unsigned short*)(base + 72 * MB);
        unsigned short* Wth  = (unsigned short*)(base + 80 * MB);
        unsigned short* Wtl  = (unsigned short*)(base + 82 * MB);
        float*          scrp = (float*)(base + 84 * MB);

        hipLaunchKernelGGL(convert_split, dim3(2048), blk, 0, stream,
                           x, xh, xl, (int)(SZ / 4));
        hipLaunchKernelGGL(transpose_split, dim3(DIM / 32, DIM / 32), blk, 0, stream,
                           Wq, Wth, Wtl);
        hipLaunchKernelGGL(gemm_mfma_split, dim3(M / 128, N / 64), blk, 0, stream,
                           xh, xl, Wth, Wtl, bq, scrp, M, N, K);
    }
}

// Round 4
// 375.030 us; speedup vs baseline: 3.1892x; 3.1892x over previous
//
#include <hip/hip_runtime.h>

#define NUMH 16
#define HD   64
#define SEQ  2048
#define NB   2
#define DIM  1024
#define MROWS (NB * SEQ)

typedef __attribute__((ext_vector_type(8))) short short8;   // 8 bf16 = 4 VGPR
typedef __attribute__((ext_vector_type(4))) float f32x4;    // MFMA accumulator

__device__ inline unsigned short bf16_rn(float f) {
    unsigned u = __float_as_uint(f);
    return (unsigned short)((u + 0x7FFFu + ((u >> 16) & 1u)) >> 16);
}
__device__ inline float bf16f(unsigned short h) {
    return __uint_as_float(((unsigned)h) << 16);
}

// ---------------------------------------------------------------------------
// fp32 -> bf16 hi/lo split, elementwise ([M][K] kept)
// ---------------------------------------------------------------------------
__global__ void convert_split(const float* __restrict__ in,
                              unsigned short* __restrict__ hi,
                              unsigned short* __restrict__ lo, int n4)
{
    for (int i = blockIdx.x * blockDim.x + threadIdx.x; i < n4;
         i += gridDim.x * blockDim.x) {
        const float4 v = ((const float4*)in)[i];
        ushort4 h, l;
        h.x = bf16_rn(v.x); l.x = bf16_rn(v.x - bf16f(h.x));
        h.y = bf16_rn(v.y); l.y = bf16_rn(v.y - bf16f(h.y));
        h.z = bf16_rn(v.z); l.z = bf16_rn(v.z - bf16f(h.z));
        h.w = bf16_rn(v.w); l.w = bf16_rn(v.w - bf16f(h.w));
        ((ushort4*)hi)[i] = h;
        ((ushort4*)lo)[i] = l;
    }
}

// ---------------------------------------------------------------------------
// W [K][N] fp32 -> Wt_hi/Wt_lo [N][K] bf16 (transpose + split)
// ---------------------------------------------------------------------------
__global__ __launch_bounds__(256)
void transpose_split(const float* __restrict__ W,
                     unsigned short* __restrict__ th,
                     unsigned short* __restrict__ tl)
{
    __shared__ float Ls[32][33];
    const int tx = threadIdx.x & 31, ty = threadIdx.x >> 5;   // 32 x 8
    const int k0 = blockIdx.x * 32, n0 = blockIdx.y * 32;
#pragma unroll
    for (int i = 0; i < 4; ++i)
        Ls[ty + 8 * i][tx] = W[(size_t)(k0 + ty + 8 * i) * DIM + n0 + tx];
    __syncthreads();
#pragma unroll
    for (int i = 0; i < 4; ++i) {
        const float f = Ls[tx][ty + 8 * i];
        const unsigned short h = bf16_rn(f);
        const unsigned short l = bf16_rn(f - bf16f(h));
        th[(size_t)(n0 + ty + 8 * i) * DIM + k0 + tx] = h;
        tl[(size_t)(n0 + ty + 8 * i) * DIM + k0 + tx] = l;
    }
}

// ---------------------------------------------------------------------------
// bf16-split MFMA GEMM: out = (Ah+Al)[M,K] @ (Bh+Bl)[N,K]^T + bias.
// 3 passes: hi*hi + hi*lo + lo*hi (lo*lo dropped, ~2^-18 rel).
// Tile 128x64, 4 waves (2x2), wave = 64x32 = 4x2 16x16 frags, K-step 32.
// EPI 0: fp32 [M][DIM] -> outF
// EPI 1: bf16 h/l scatter [B,H,S,Hd]   (Q, K)
// EPI 2: bf16 h  scatter  [B,H,Hd,S]   (V transposed; packed ushort4 stores)
// ---------------------------------------------------------------------------
template<int EPI>
__global__ __launch_bounds__(256, 2)
void gemm_split(const unsigned short* __restrict__ Ah,
                const unsigned short* __restrict__ Al,
                const unsigned short* __restrict__ Bh,
                const unsigned short* __restrict__ Bl,
                const float* __restrict__ bias,
                float* __restrict__ outF,
                unsigned short* __restrict__ outH,
                unsigned short* __restrict__ outL)
{
    __shared__ unsigned short AsH[128][32];
    __shared__ unsigned short AsL[128][32];
    __shared__ unsigned short BsH[64][32];
    __shared__ unsigned short BsL[64][32];

    const int tid  = threadIdx.x;
    const int m0   = blockIdx.x * 128;
    const int n0   = blockIdx.y * 64;
    const int wid  = tid >> 6;
    const int lane = tid & 63;
    const int wr   = wid >> 1;
    const int wc   = wid & 1;
    const int fr   = lane & 15;
    const int fg   = lane >> 4;
    const int K    = DIM;

    f32x4 acc[4][2];
#pragma unroll
    for (int i = 0; i < 4; ++i)
#pragma unroll
        for (int j = 0; j < 2; ++j) { f32x4 z = {0.f, 0.f, 0.f, 0.f}; acc[i][j] = z; }

    const int row0 = tid >> 2;           // 0..63
    const int k80  = (tid & 3) * 8;      // 0,8,16,24

    for (int kt = 0; kt < K; kt += 32) {
        __syncthreads();
        *(short8*)&AsH[row0][k80]      = *(const short8*)&Ah[(size_t)(m0 + row0) * K + kt + k80];
        *(short8*)&AsH[row0 + 64][k80] = *(const short8*)&Ah[(size_t)(m0 + row0 + 64) * K + kt + k80];
        *(short8*)&AsL[row0][k80]      = *(const short8*)&Al[(size_t)(m0 + row0) * K + kt + k80];
        *(short8*)&AsL[row0 + 64][k80] = *(const short8*)&Al[(size_t)(m0 + row0 + 64) * K + kt + k80];
        *(short8*)&BsH[row0][k80]      = *(const short8*)&Bh[(size_t)(n0 + row0) * K + kt + k80];
        *(short8*)&BsL[row0][k80]      = *(const short8*)&Bl[(size_t)(n0 + row0) * K + kt + k80];
        __syncthreads();

        short8 afh[4], afl[4], bfh[2], bfl[2];
#pragma unroll
        for (int i = 0; i < 4; ++i) {
            afh[i] = *(const short8*)&AsH[wr * 64 + i * 16 + fr][fg * 8];
            afl[i] = *(const short8*)&AsL[wr * 64 + i * 16 + fr][fg * 8];
        }
#pragma unroll
        for (int j = 0; j < 2; ++j) {
            bfh[j] = *(const short8*)&BsH[wc * 32 + j * 16 + fr][fg * 8];
            bfl[j] = *(const short8*)&BsL[wc * 32 + j * 16 + fr][fg * 8];
        }
#pragma unroll
        for (int i = 0; i < 4; ++i)
#pragma unroll
            for (int j = 0; j < 2; ++j) {
                acc[i][j] = __builtin_amdgcn_mfma_f32_16x16x32_bf16(afl[i], bfh[j], acc[i][j], 0, 0, 0);
                acc[i][j] = __builtin_amdgcn_mfma_f32_16x16x32_bf16(afh[i], bfl[j], acc[i][j], 0, 0, 0);
                acc[i][j] = __builtin_amdgcn_mfma_f32_16x16x32_bf16(afh[i], bfh[j], acc[i][j], 0, 0, 0);
            }
    }

    // C/D layout (HW-verified m89/m91): col = lane&15, row = (lane>>4)*4 + reg
#pragma unroll
    for (int i = 0; i < 4; ++i)
#pragma unroll
        for (int j = 0; j < 2; ++j) {
            const int col = n0 + wc * 32 + j * 16 + fr;
            const float bv = bias[col];
            if (EPI == 2) {
                const int row = m0 + wr * 64 + i * 16 + fg * 4;   // 4 consecutive s
                const int b  = row >> 11;
                const int s  = row & (SEQ - 1);
                const int hh = col >> 6;
                const int hd = col & (HD - 1);
                ushort4 pk;
                pk.x = bf16_rn(acc[i][j][0] + bv);
                pk.y = bf16_rn(acc[i][j][1] + bv);
                pk.z = bf16_rn(acc[i][j][2] + bv);
                pk.w = bf16_rn(acc[i][j][3] + bv);
                *(ushort4*)&outH[((size_t)(b * NUMH + hh) * HD + hd) * SEQ + s] = pk;
            } else {
#pragma unroll
                for (int r = 0; r < 4; ++r) {
                    const int row = m0 + wr * 64 + i * 16 + fg * 4 + r;
                    const float v = acc[i][j][r] + bv;
                    if (EPI == 0) {
                        outF[(size_t)row * DIM + col] = v;
                    } else {   // EPI == 1
                        const int b  = row >> 11;
                        const int s  = row & (SEQ - 1);
                        const int hh = col >> 6;
                        const int hd = col & (HD - 1);
                        const size_t idx = ((size_t)(b * NUMH + hh) * SEQ + s) * HD + hd;
                        const unsigned short hv = bf16_rn(v);
                        outH[idx] = hv;
                        outL[idx] = bf16_rn(v - bf16f(hv));
                    }
                }
            }
        }
}

// ---------------------------------------------------------------------------
// MFMA flash attention, causal. Block = (b,h,64-q-tile), 4 warps x 16 q-rows.
// Q/K bf16 h/l [B,H,S,Hd]; V bf16 [B,H,Hd,S] (pre-transposed).
// QK^T: 3-pass split. PV: pure bf16 (P in [0,1], error ~5e-4).
// Softmax in-register: C/D row = (lane>>4)*4+reg -> per-reg m/l, 16-lane
// shfl_xor butterflies; O-rescale is per-reg (no cross-lane fixup).
// ctx written as bf16 h/l [M][DIM] for the final split-GEMM.
// ---------------------------------------------------------------------------
__global__ __launch_bounds__(256, 3)
void attn_mfma(const unsigned short* __restrict__ Qh, const unsigned short* __restrict__ Ql,
               const unsigned short* __restrict__ Kh, const unsigned short* __restrict__ Kl,
               const unsigned short* __restrict__ Vt,
               unsigned short* __restrict__ ctxH, unsigned short* __restrict__ ctxL)
{
    __shared__ unsigned short KsH[64][72];   // [k'][d], stride 72 vs bank stride
    __shared__ unsigned short KsL[64][72];
    __shared__ unsigned short Vs[64][72];    // [d][k]  (Vt rows are d!)
    __shared__ unsigned short Ps[4][16][72]; // warp-private P [q_local][k_local]

    const int tid  = threadIdx.x;
    const int w    = tid >> 6;
    const int lane = tid & 63;
    const int lc   = lane & 15;
    const int g    = lane >> 4;

    const int bh = blockIdx.x >> 5;          // b*16 + head
    const int qt = blockIdx.x & 31;
    const int q0 = qt * 64;
    const int bb = bh >> 4;
    const int hq = bh & 15;

    const size_t kqBase = (size_t)bh * SEQ * HD;
    const size_t vBase  = (size_t)bh * HD * SEQ;

    // Q A-frags in registers (once per block): row q = q0+w*16+lc, d = s*32+g*8+j
    short8 qfh[2], qfl[2];
    {
        const size_t qr = kqBase + (size_t)(q0 + w * 16 + lc) * HD;
        qfh[0] = *(const short8*)&Qh[qr + g * 8];
        qfh[1] = *(const short8*)&Qh[qr + 32 + g * 8];
        qfl[0] = *(const short8*)&Ql[qr + g * 8];
        qfl[1] = *(const short8*)&Ql[qr + 32 + g * 8];
    }

    f32x4 o[4];
#pragma unroll
    for (int f4 = 0; f4 < 4; ++f4) { f32x4 z = {0.f, 0.f, 0.f, 0.f}; o[f4] = z; }
    float mrun[4], lrun[4];
#pragma unroll
    for (int r = 0; r < 4; ++r) { mrun[r] = -1e30f; lrun[r] = 0.f; }

    const int srow = w * 16 + (lane >> 2);   // staging row 0..63
    const int scol = (lane & 3) * 16;        // staging col (bf16 elems)

    for (int kt = 0; kt <= qt; ++kt) {
        const int k0 = kt * 64;
        __syncthreads();   // prev-tile K/V reads complete
        {
            const size_t kg = kqBase + (size_t)(k0 + srow) * HD + scol;
            const short8 a = *(const short8*)&Kh[kg];
            const short8 b = *(const short8*)&Kh[kg + 8];
            const short8 c = *(const short8*)&Kl[kg];
            const short8 d = *(const short8*)&Kl[kg + 8];
            const size_t vg = vBase + (size_t)srow * SEQ + k0 + scol;
            const short8 e = *(const short8*)&Vt[vg];
            const short8 f = *(const short8*)&Vt[vg + 8];
            *(short8*)&KsH[srow][scol]     = a;
            *(short8*)&KsH[srow][scol + 8] = b;
            *(short8*)&KsL[srow][scol]     = c;
            *(short8*)&KsL[srow][scol + 8] = d;
            *(short8*)&Vs[srow][scol]      = e;
            *(short8*)&Vs[srow][scol + 8]  = f;
        }
        __syncthreads();   // tile staged

        // ---- scores: S[q][k'] , 4 k-frags x (2 d-steps x 3 split passes) ----
        f32x4 sf[4];
#pragma unroll
        for (int f4 = 0; f4 < 4; ++f4) {
            f32x4 s = {0.f, 0.f, 0.f, 0.f};
#pragma unroll
            for (int s2 = 0; s2 < 2; ++s2) {
                const short8 kh = *(const short8*)&KsH[f4 * 16 + lc][s2 * 32 + g * 8];
                const short8 kl = *(const short8*)&KsL[f4 * 16 + lc][s2 * 32 + g * 8];
                s = __builtin_amdgcn_mfma_f32_16x16x32_bf16(qfl[s2], kh, s, 0, 0, 0);
                s = __builtin_amdgcn_mfma_f32_16x16x32_bf16(qfh[s2], kl, s, 0, 0, 0);
                s = __builtin_amdgcn_mfma_f32_16x16x32_bf16(qfh[s2], kh, s, 0, 0, 0);
            }
            sf[f4] = s;
        }

        // ---- mask + scale + row-max ----
        const bool diag = (kt == qt);
        float rowm[4];
#pragma unroll
        for (int r = 0; r < 4; ++r) rowm[r] = -1e30f;
#pragma unroll
        for (int f4 = 0; f4 < 4; ++f4)
#pragma unroll
            for (int r = 0; r < 4; ++r) {
                float sv = sf[f4][r] * 0.125f;
                if (diag && (f4 * 16 + lc > w * 16 + g * 4 + r)) sv = -1e30f;
                sf[f4][r] = sv;
                rowm[r] = fmaxf(rowm[r], sv);
            }
#pragma unroll
        for (int off = 1; off < 16; off <<= 1)
#pragma unroll
            for (int r = 0; r < 4; ++r)
                rowm[r] = fmaxf(rowm[r], __shfl_xor(rowm[r], off));

        // ---- online-softmax update (per-reg, rescale O) ----
        float psum[4];
#pragma unroll
        for (int r = 0; r < 4; ++r) {
            const float mn = fmaxf(mrun[r], rowm[r]);
            const float sc = __expf(mrun[r] - mn);
            mrun[r] = mn;
            lrun[r] *= sc;
            psum[r] = 0.f;
#pragma unroll
            for (int f4 = 0; f4 < 4; ++f4) o[f4][r] *= sc;
        }
#pragma unroll
        for (int f4 = 0; f4 < 4; ++f4)
#pragma unroll
            for (int r = 0; r < 4; ++r) {
                const float p = __expf(sf[f4][r] - mrun[r]);
                psum[r] += p;
                Ps[w][g * 4 + r][f4 * 16 + lc] = bf16_rn(p);
            }
#pragma unroll
        for (int off = 1; off < 16; off <<= 1)
#pragma unroll
            for (int r = 0; r < 4; ++r)
                psum[r] += __shfl_xor(psum[r], off);
#pragma unroll
        for (int r = 0; r < 4; ++r) lrun[r] += psum[r];

        // warp-private P: order write->read via lgkmcnt (no barrier needed)
        asm volatile("s_waitcnt lgkmcnt(0)" ::: "memory");
        __builtin_amdgcn_sched_barrier(0);

        // ---- PV: O[q][d] += P[q][k] @ V[k][d] ----
        const short8 pa0 = *(const short8*)&Ps[w][lc][g * 8];
        const short8 pa1 = *(const short8*)&Ps[w][lc][32 + g * 8];
#pragma unroll
        for (int f4 = 0; f4 < 4; ++f4) {
            const short8 v0 = *(const short8*)&Vs[f4 * 16 + lc][g * 8];
            const short8 v1 = *(const short8*)&Vs[f4 * 16 + lc][32 + g * 8];
            o[f4] = __builtin_amdgcn_mfma_f32_16x16x32_bf16(pa0, v0, o[f4], 0, 0, 0);
            o[f4] = __builtin_amdgcn_mfma_f32_16x16x32_bf16(pa1, v1, o[f4], 0, 0, 0);
        }
    }

    // ---- epilogue: O /= l, write ctx bf16 h/l [M][DIM] ----
    float inv[4];
#pragma unroll
    for (int r = 0; r < 4; ++r) inv[r] = 1.f / lrun[r];
    const size_t orow0 = (size_t)bb * SEQ + q0 + w * 16 + g * 4;
#pragma unroll
    for (int r = 0; r < 4; ++r) {
        const size_t rbase = (orow0 + r) * DIM + hq * HD;
#pragma unroll
        for (int f4 = 0; f4 < 4; ++f4) {
            const float v = o[f4][r] * inv[r];
            const unsigned short hv = bf16_rn(v);
            ctxH[rbase + f4 * 16 + lc] = hv;
            ctxL[rbase + f4 * 16 + lc] = bf16_rn(v - bf16f(hv));
        }
    }
}

// ---------------------------------------------------------------------------
extern "C" void kernel_launch(void* const* d_in, const int* in_sizes, int n_in,
                              void* d_out, int out_size, void* d_ws, size_t ws_size,
                              hipStream_t stream)
{
    const float* x  = (const float*)d_in[0];
    const float* Wq = (const float*)d_in[1];
    const float* bq = (const float*)d_in[2];
    const float* Wk = (const float*)d_in[3];
    const float* bk = (const float*)d_in[4];
    const float* Wv = (const float*)d_in[5];
    const float* bv = (const float*)d_in[6];
    const float* Wo = (const float*)d_in[7];
    const float* bo = (const float*)d_in[8];

    // 60 MB workspace map (64 MB proven available in round 0/3)
    char* base = (char*)d_ws;
    const size_t MB = 1024 * 1024;
    unsigned short* Qh_ = (unsigned short*)(base + 0 * MB);
    unsigned short* Ql_ = (unsigned short*)(base + 8 * MB);
    unsigned short* Kh_ = (unsigned short*)(base + 16 * MB);
    unsigned short* Kl_ = (unsigned short*)(base + 24 * MB);
    unsigned short* Vt_ = (unsigned short*)(base + 32 * MB);
    unsigned short* xh  = (unsigned short*)(base + 40 * MB);   // reused as ctxH
    unsigned short* xl  = (unsigned short*)(base + 48 * MB);   // reused as ctxL
    unsigned short* Wth = (unsigned short*)(base + 56 * MB);
    unsigned short* Wtl = (unsigned short*)(base + 58 * MB);

    dim3 blk(256);
    dim3 gg(MROWS / 128, DIM / 64);     // (32,16)
    dim3 gt(DIM / 32, DIM / 32);        // (32,32)

    hipLaunchKernelGGL(convert_split, dim3(2048), blk, 0, stream,
                       x, xh, xl, MROWS * DIM / 4);

    hipLaunchKernelGGL(transpose_split, gt, blk, 0, stream, Wq, Wth, Wtl);
    hipLaunchKernelGGL((gemm_split<1>), gg, blk, 0, stream,
                       xh, xl, Wth, Wtl, bq, nullptr, Qh_, Ql_);

    hipLaunchKernelGGL(transpose_split, gt, blk, 0, stream, Wk, Wth, Wtl);
    hipLaunchKernelGGL((gemm_split<1>), gg, blk, 0, stream,
                       xh, xl, Wth, Wtl, bk, nullptr, Kh_, Kl_);

    hipLaunchKernelGGL(transpose_split, gt, blk, 0, stream, Wv, Wth, Wtl);
    hipLaunchKernelGGL((gemm_split<2>), gg, blk, 0, stream,
                       xh, xl, Wth, Wtl, bv, nullptr, Vt_, nullptr);

    hipLaunchKernelGGL(attn_mfma, dim3(NB * NUMH * (SEQ / 64)), blk, 0, stream,
                       Qh_, Ql_, Kh_, Kl_, Vt_, xh, xl);   // ctx -> xh/xl (aliased)

    hipLaunchKernelGGL(transpose_split, gt, blk, 0, stream, Wo, Wth, Wtl);
    hipLaunchKernelGGL((gemm_split<0>), gg, blk, 0, stream,
                       xh, xl, Wth, Wtl, bo, (float*)d_out, nullptr, nullptr);
}

// Round 5
// 324.398 us; speedup vs baseline: 3.6869x; 1.1561x over previous
//
#include <hip/hip_runtime.h>

#define NUMH 16
#define HD   64
#define SEQ  2048
#define NB   2
#define DIM  1024
#define MROWS (NB * SEQ)

typedef __attribute__((ext_vector_type(8))) short short8;
typedef __attribute__((ext_vector_type(4))) float f32x4;
typedef unsigned short u16;
typedef unsigned int u32;

__device__ inline u16 bf16_rn(float f) {
    unsigned u = __float_as_uint(f);
    return (u16)((u + 0x7FFFu + ((u >> 16) & 1u)) >> 16);
}
__device__ inline float bf16f(u16 h) {
    return __uint_as_float(((unsigned)h) << 16);
}

// ---------------------------------------------------------------------------
// fp32 -> bf16 hi/lo split, elementwise ([M][K] kept)
// ---------------------------------------------------------------------------
__global__ void convert_split(const float* __restrict__ in,
                              u16* __restrict__ hi, u16* __restrict__ lo, int n4)
{
    for (int i = blockIdx.x * blockDim.x + threadIdx.x; i < n4;
         i += gridDim.x * blockDim.x) {
        const float4 v = ((const float4*)in)[i];
        ushort4 h, l;
        h.x = bf16_rn(v.x); l.x = bf16_rn(v.x - bf16f(h.x));
        h.y = bf16_rn(v.y); l.y = bf16_rn(v.y - bf16f(h.y));
        h.z = bf16_rn(v.z); l.z = bf16_rn(v.z - bf16f(h.z));
        h.w = bf16_rn(v.w); l.w = bf16_rn(v.w - bf16f(h.w));
        ((ushort4*)hi)[i] = h;
        ((ushort4*)lo)[i] = l;
    }
}

// ---------------------------------------------------------------------------
// W [K][N] fp32 -> Wt_hi/Wt_lo [N][K] bf16 (transpose + split), * scale
// ---------------------------------------------------------------------------
__global__ __launch_bounds__(256)
void transpose_split(const float* __restrict__ W,
                     u16* __restrict__ th, u16* __restrict__ tl, float scale)
{
    __shared__ float Ls[32][33];
    const int tx = threadIdx.x & 31, ty = threadIdx.x >> 5;
    const int k0 = blockIdx.x * 32, n0 = blockIdx.y * 32;
#pragma unroll
    for (int i = 0; i < 4; ++i)
        Ls[ty + 8 * i][tx] = W[(size_t)(k0 + ty + 8 * i) * DIM + n0 + tx];
    __syncthreads();
#pragma unroll
    for (int i = 0; i < 4; ++i) {
        const float f = Ls[tx][ty + 8 * i] * scale;
        const u16 h = bf16_rn(f);
        const u16 l = bf16_rn(f - bf16f(h));
        th[(size_t)(n0 + ty + 8 * i) * DIM + k0 + tx] = h;
        tl[(size_t)(n0 + ty + 8 * i) * DIM + k0 + tx] = l;
    }
}

// ---------------------------------------------------------------------------
// bf16-split MFMA GEMM + T14 register-prefetch of next K-tile.
// EPI 0: fp32 [M][DIM]; EPI 1: bf16 h/l scatter [B,H,S,Hd]; EPI 2: bf16 h
// scatter [B,H,Hd,S] (V transposed, packed ushort4).
// ---------------------------------------------------------------------------
template<int EPI>
__global__ __launch_bounds__(256, 2)
void gemm_split(const u16* __restrict__ Ah, const u16* __restrict__ Al,
                const u16* __restrict__ Bh, const u16* __restrict__ Bl,
                const float* __restrict__ bias, float bscale,
                float* __restrict__ outF, u16* __restrict__ outH,
                u16* __restrict__ outL)
{
    __shared__ u16 AsH[128][32];
    __shared__ u16 AsL[128][32];
    __shared__ u16 BsH[64][32];
    __shared__ u16 BsL[64][32];

    const int tid  = threadIdx.x;
    const int m0   = blockIdx.x * 128;
    const int n0   = blockIdx.y * 64;
    const int wid  = tid >> 6;
    const int lane = tid & 63;
    const int wr   = wid >> 1;
    const int wc   = wid & 1;
    const int fr   = lane & 15;
    const int fg   = lane >> 4;
    const int K    = DIM;

    f32x4 acc[4][2];
#pragma unroll
    for (int i = 0; i < 4; ++i)
#pragma unroll
        for (int j = 0; j < 2; ++j) { f32x4 z = {0.f, 0.f, 0.f, 0.f}; acc[i][j] = z; }

    const int row0 = tid >> 2;
    const int k80  = (tid & 3) * 8;

    short8 pf[6];
    auto LOAD = [&](int kt) {
        pf[0] = *(const short8*)&Ah[(size_t)(m0 + row0) * K + kt + k80];
        pf[1] = *(const short8*)&Ah[(size_t)(m0 + row0 + 64) * K + kt + k80];
        pf[2] = *(const short8*)&Al[(size_t)(m0 + row0) * K + kt + k80];
        pf[3] = *(const short8*)&Al[(size_t)(m0 + row0 + 64) * K + kt + k80];
        pf[4] = *(const short8*)&Bh[(size_t)(n0 + row0) * K + kt + k80];
        pf[5] = *(const short8*)&Bl[(size_t)(n0 + row0) * K + kt + k80];
    };
    LOAD(0);

    for (int kt = 0; kt < K; kt += 32) {
        __syncthreads();
        *(short8*)&AsH[row0][k80]      = pf[0];
        *(short8*)&AsH[row0 + 64][k80] = pf[1];
        *(short8*)&AsL[row0][k80]      = pf[2];
        *(short8*)&AsL[row0 + 64][k80] = pf[3];
        *(short8*)&BsH[row0][k80]      = pf[4];
        *(short8*)&BsL[row0][k80]      = pf[5];
        __syncthreads();
        if (kt + 32 < K) LOAD(kt + 32);

        short8 afh[4], afl[4], bfh[2], bfl[2];
#pragma unroll
        for (int i = 0; i < 4; ++i) {
            afh[i] = *(const short8*)&AsH[wr * 64 + i * 16 + fr][fg * 8];
            afl[i] = *(const short8*)&AsL[wr * 64 + i * 16 + fr][fg * 8];
        }
#pragma unroll
        for (int j = 0; j < 2; ++j) {
            bfh[j] = *(const short8*)&BsH[wc * 32 + j * 16 + fr][fg * 8];
            bfl[j] = *(const short8*)&BsL[wc * 32 + j * 16 + fr][fg * 8];
        }
#pragma unroll
        for (int i = 0; i < 4; ++i)
#pragma unroll
            for (int j = 0; j < 2; ++j) {
                acc[i][j] = __builtin_amdgcn_mfma_f32_16x16x32_bf16(afl[i], bfh[j], acc[i][j], 0, 0, 0);
                acc[i][j] = __builtin_amdgcn_mfma_f32_16x16x32_bf16(afh[i], bfl[j], acc[i][j], 0, 0, 0);
                acc[i][j] = __builtin_amdgcn_mfma_f32_16x16x32_bf16(afh[i], bfh[j], acc[i][j], 0, 0, 0);
            }
    }

#pragma unroll
    for (int i = 0; i < 4; ++i)
#pragma unroll
        for (int j = 0; j < 2; ++j) {
            const int col = n0 + wc * 32 + j * 16 + fr;
            const float bv = bias[col] * bscale;
            if (EPI == 2) {
                const int row = m0 + wr * 64 + i * 16 + fg * 4;
                const int b  = row >> 11;
                const int s  = row & (SEQ - 1);
                const int hh = col >> 6;
                const int hd = col & (HD - 1);
                ushort4 pk;
                pk.x = bf16_rn(acc[i][j][0] + bv);
                pk.y = bf16_rn(acc[i][j][1] + bv);
                pk.z = bf16_rn(acc[i][j][2] + bv);
                pk.w = bf16_rn(acc[i][j][3] + bv);
                *(ushort4*)&outH[((size_t)(b * NUMH + hh) * HD + hd) * SEQ + s] = pk;
            } else {
#pragma unroll
                for (int r = 0; r < 4; ++r) {
                    const int row = m0 + wr * 64 + i * 16 + fg * 4 + r;
                    const float v = acc[i][j][r] + bv;
                    if (EPI == 0) {
                        outF[(size_t)row * DIM + col] = v;
                    } else {
                        const int b  = row >> 11;
                        const int s  = row & (SEQ - 1);
                        const int hh = col >> 6;
                        const int hd = col & (HD - 1);
                        const size_t idx = ((size_t)(b * NUMH + hh) * SEQ + s) * HD + hd;
                        const u16 hv = bf16_rn(v);
                        outH[idx] = hv;
                        outL[idx] = bf16_rn(v - bf16f(hv));
                    }
                }
            }
        }
}

// ---------------------------------------------------------------------------
// MFMA flash attention v2: swapped QK^T (S^T = mfma(K,Q)), causal pairing
// (block = q-tiles {p, 31-p}: uniform 33 units, shared K/V staging),
// XOR-swizzled dense LDS, register-prefetch staging, bpermute P-redistribute.
// Q pre-scaled by 0.125 (folded into Wq/bq). Grid 512 = 2 blocks/CU.
// ---------------------------------------------------------------------------
__global__ __launch_bounds__(256, 2)
void attn_mfma2(const u16* __restrict__ Qh, const u16* __restrict__ Ql,
                const u16* __restrict__ Kh, const u16* __restrict__ Kl,
                const u16* __restrict__ Vt,
                u16* __restrict__ ctxH, u16* __restrict__ ctxL)
{
    __shared__ u16 KsH[64 * 64];
    __shared__ u16 KsL[64 * 64];
    __shared__ u16 Vs [64 * 64];

    const int tid  = threadIdx.x;
    const int w    = tid >> 6;
    const int lane = tid & 63;
    const int lc   = lane & 15;
    const int g    = lane >> 4;

    const int bh = blockIdx.x >> 4;
    const int p  = blockIdx.x & 15;
    const int qA = p, qB = 31 - p;
    const int NT = 32 - p;                  // staged tiles: kt = 0..qB
    const int bb = bh >> 4, hq = bh & 15;
    const size_t kqBase = (size_t)bh * SEQ * HD;
    const size_t vBase  = (size_t)bh * HD * SEQ;

    // Q B-frags: lane holds Q[q = lc][d = s2*32 + g*8 + j]
    short8 qhA[2], qlA[2], qhB[2], qlB[2];
    {
        const size_t ra = kqBase + (size_t)(qA * 64 + w * 16 + lc) * HD;
        const size_t rb = kqBase + (size_t)(qB * 64 + w * 16 + lc) * HD;
        qhA[0] = *(const short8*)&Qh[ra + g * 8];  qhA[1] = *(const short8*)&Qh[ra + 32 + g * 8];
        qlA[0] = *(const short8*)&Ql[ra + g * 8];  qlA[1] = *(const short8*)&Ql[ra + 32 + g * 8];
        qhB[0] = *(const short8*)&Qh[rb + g * 8];  qhB[1] = *(const short8*)&Qh[rb + 32 + g * 8];
        qlB[0] = *(const short8*)&Ql[rb + g * 8];  qlB[1] = *(const short8*)&Ql[rb + 32 + g * 8];
    }

    f32x4 oA[4], oB[4];
#pragma unroll
    for (int f4 = 0; f4 < 4; ++f4) {
        f32x4 z = {0.f, 0.f, 0.f, 0.f};
        oA[f4] = z; oB[f4] = z;
    }
    float mA = -1e30f, lA = 0.f, mB = -1e30f, lB = 0.f;

    // staging: thread -> row tid>>2, 2x16B at col (tid&3)*16 ; swizzle ^((row&7)<<3)
    const int srow = tid >> 2;
    const int scol = (tid & 3) * 16;
    const int sw   = (srow & 7) << 3;
    const int so1  = srow * 64 + (scol ^ sw);
    const int so2  = srow * 64 + ((scol + 8) ^ sw);
    const int rsw  = (lc & 7) << 3;          // read-side swizzle (row = f4*16+lc)

    short8 pf[6];
    auto LOADT = [&](int kt) {
        const size_t kg = kqBase + (size_t)(kt * 64 + srow) * HD + scol;
        pf[0] = *(const short8*)&Kh[kg];      pf[1] = *(const short8*)&Kh[kg + 8];
        pf[2] = *(const short8*)&Kl[kg];      pf[3] = *(const short8*)&Kl[kg + 8];
        const size_t vg = vBase + (size_t)srow * SEQ + kt * 64 + scol;
        pf[4] = *(const short8*)&Vt[vg];      pf[5] = *(const short8*)&Vt[vg + 8];
    };
    LOADT(0);

    for (int kt = 0; kt < NT; ++kt) {
        __syncthreads();                     // prev tile's LDS reads done
        *(short8*)&KsH[so1] = pf[0];  *(short8*)&KsH[so2] = pf[1];
        *(short8*)&KsL[so1] = pf[2];  *(short8*)&KsL[so2] = pf[3];
        *(short8*)&Vs [so1] = pf[4];  *(short8*)&Vs [so2] = pf[5];
        __syncthreads();                     // tile ready
        if (kt + 1 < NT) LOADT(kt + 1);      // prefetch hides under compute

        const bool actA = (kt <= qA);
        const int  k0   = kt * 64;

        // ---- scores: S^T[k][q] = mfma(K-frag, Q-frag), K frags read once ----
        f32x4 sA[4], sB[4];
#pragma unroll
        for (int f4 = 0; f4 < 4; ++f4) {
            f32x4 a = {0.f, 0.f, 0.f, 0.f}, b = {0.f, 0.f, 0.f, 0.f};
#pragma unroll
            for (int s2 = 0; s2 < 2; ++s2) {
                const int off = (f4 * 16 + lc) * 64 + ((s2 * 32 + g * 8) ^ rsw);
                const short8 kh = *(const short8*)&KsH[off];
                const short8 kl = *(const short8*)&KsL[off];
                if (actA) {
                    a = __builtin_amdgcn_mfma_f32_16x16x32_bf16(kh, qlA[s2], a, 0, 0, 0);
                    a = __builtin_amdgcn_mfma_f32_16x16x32_bf16(kl, qhA[s2], a, 0, 0, 0);
                    a = __builtin_amdgcn_mfma_f32_16x16x32_bf16(kh, qhA[s2], a, 0, 0, 0);
                }
                b = __builtin_amdgcn_mfma_f32_16x16x32_bf16(kh, qlB[s2], b, 0, 0, 0);
                b = __builtin_amdgcn_mfma_f32_16x16x32_bf16(kl, qhB[s2], b, 0, 0, 0);
                b = __builtin_amdgcn_mfma_f32_16x16x32_bf16(kh, qhB[s2], b, 0, 0, 0);
            }
            sA[f4] = a; sB[f4] = b;
        }

        // ---- per-q-tile softmax + in-register P redistribute ----
        u32 pbA[2][4], pbB[2][4];
        const int a0 = (((g & 1) * 2 + 0) * 16 + lc) * 4;   // bpermute byte addrs
        const int a1 = (((g & 1) * 2 + 1) * 16 + lc) * 4;
        const bool hi = ((g >> 1) & 1) != 0;

        auto SOFTMAX = [&](f32x4* sf, float& m, float& l, f32x4* o,
                           int qt, u32 pb[2][4]) {
            const bool diag = (kt == qt);
            const int  qg   = qt * 64 + w * 16 + lc;
            float pm = -1e30f;
#pragma unroll
            for (int f4 = 0; f4 < 4; ++f4)
#pragma unroll
                for (int r = 0; r < 4; ++r) {
                    float sv = sf[f4][r];
                    if (diag && (k0 + f4 * 16 + g * 4 + r > qg)) sv = -1e30f;
                    sf[f4][r] = sv;
                    pm = fmaxf(pm, sv);
                }
            pm = fmaxf(pm, __shfl_xor(pm, 16));
            pm = fmaxf(pm, __shfl_xor(pm, 32));
            const float mn = fmaxf(m, pm);
            const float sc = __expf(m - mn);
            m = mn; l *= sc;
#pragma unroll
            for (int f4 = 0; f4 < 4; ++f4) o[f4] *= sc;
            float ps = 0.f;
            u32 pk[4][2];
#pragma unroll
            for (int f4 = 0; f4 < 4; ++f4)
#pragma unroll
                for (int pr = 0; pr < 2; ++pr) {
                    const float p0 = __expf(sf[f4][pr * 2 + 0] - mn);
                    const float p1 = __expf(sf[f4][pr * 2 + 1] - mn);
                    ps += p0 + p1;
                    pk[f4][pr] = (u32)bf16_rn(p0) | ((u32)bf16_rn(p1) << 16);
                }
            ps += __shfl_xor(ps, 16);
            ps += __shfl_xor(ps, 32);
            l += ps;
            // pb[s2][mm]: P^T[k = s2*32 + g*8 + 2mm .. +1][q = lc]
#pragma unroll
            for (int s2 = 0; s2 < 2; ++s2)
#pragma unroll
                for (int mm = 0; mm < 4; ++mm) {
                    const int addr = (mm < 2) ? a0 : a1;
                    const u32 t0 = (u32)__builtin_amdgcn_ds_bpermute(addr, (int)pk[s2 * 2 + 0][mm & 1]);
                    const u32 t1 = (u32)__builtin_amdgcn_ds_bpermute(addr, (int)pk[s2 * 2 + 1][mm & 1]);
                    pb[s2][mm] = hi ? t1 : t0;
                }
        };

        if (actA) SOFTMAX(sA, mA, lA, oA, qA, pbA);
        SOFTMAX(sB, mB, lB, oB, qB, pbB);

        // ---- PV: o^T[d][q] += mfma(V^T-frag, P^T-frag), V frags read once ----
#pragma unroll
        for (int s2 = 0; s2 < 2; ++s2) {
            union { u32 u[4]; short8 s; } ua, ub;
#pragma unroll
            for (int mm = 0; mm < 4; ++mm) { ua.u[mm] = pbA[s2][mm]; ub.u[mm] = pbB[s2][mm]; }
#pragma unroll
            for (int f4 = 0; f4 < 4; ++f4) {
                const int off = (f4 * 16 + lc) * 64 + ((s2 * 32 + g * 8) ^ rsw);
                const short8 vv = *(const short8*)&Vs[off];
                if (actA) oA[f4] = __builtin_amdgcn_mfma_f32_16x16x32_bf16(vv, ua.s, oA[f4], 0, 0, 0);
                oB[f4] = __builtin_amdgcn_mfma_f32_16x16x32_bf16(vv, ub.s, oB[f4], 0, 0, 0);
            }
        }
    }

    // ---- epilogue: o^T[d][q]/l -> ctx bf16 h/l [M][DIM] ----
    const float iA = 1.f / lA, iB = 1.f / lB;
    const size_t rowA = (size_t)bb * SEQ + qA * 64 + w * 16 + lc;
    const size_t rowB = (size_t)bb * SEQ + qB * 64 + w * 16 + lc;
#pragma unroll
    for (int f4 = 0; f4 < 4; ++f4) {
        const int colb = hq * HD + f4 * 16 + g * 4;
        ushort4 h4, l4;
#pragma unroll
        for (int r = 0; r < 4; ++r) {
            const float v = oA[f4][r] * iA;
            const u16 hv = bf16_rn(v);
            ((u16*)&h4)[r] = hv;
            ((u16*)&l4)[r] = bf16_rn(v - bf16f(hv));
        }
        *(ushort4*)&ctxH[rowA * DIM + colb] = h4;
        *(ushort4*)&ctxL[rowA * DIM + colb] = l4;
#pragma unroll
        for (int r = 0; r < 4; ++r) {
            const float v = oB[f4][r] * iB;
            const u16 hv = bf16_rn(v);
            ((u16*)&h4)[r] = hv;
            ((u16*)&l4)[r] = bf16_rn(v - bf16f(hv));
        }
        *(ushort4*)&ctxH[rowB * DIM + colb] = h4;
        *(ushort4*)&ctxL[rowB * DIM + colb] = l4;
    }
}

// ---------------------------------------------------------------------------
extern "C" void kernel_launch(void* const* d_in, const int* in_sizes, int n_in,
                              void* d_out, int out_size, void* d_ws, size_t ws_size,
                              hipStream_t stream)
{
    const float* x  = (const float*)d_in[0];
    const float* Wq = (const float*)d_in[1];
    const float* bq = (const float*)d_in[2];
    const float* Wk = (const float*)d_in[3];
    const float* bk = (const float*)d_in[4];
    const float* Wv = (const float*)d_in[5];
    const float* bv = (const float*)d_in[6];
    const float* Wo = (const float*)d_in[7];
    const float* bo = (const float*)d_in[8];

    char* base = (char*)d_ws;
    const size_t MB = 1024 * 1024;
    u16* Qh_ = (u16*)(base + 0 * MB);
    u16* Ql_ = (u16*)(base + 8 * MB);
    u16* Kh_ = (u16*)(base + 16 * MB);
    u16* Kl_ = (u16*)(base + 24 * MB);
    u16* Vt_ = (u16*)(base + 32 * MB);
    u16* xh  = (u16*)(base + 40 * MB);   // reused as ctxH
    u16* xl  = (u16*)(base + 48 * MB);   // reused as ctxL
    u16* Wth = (u16*)(base + 56 * MB);
    u16* Wtl = (u16*)(base + 58 * MB);

    dim3 blk(256);
    dim3 gg(MROWS / 128, DIM / 64);
    dim3 gt(DIM / 32, DIM / 32);

    hipLaunchKernelGGL(convert_split, dim3(2048), blk, 0, stream,
                       x, xh, xl, MROWS * DIM / 4);

    // Q projection carries the 1/sqrt(Hd)=0.125 scale (exact in bf16 split)
    hipLaunchKernelGGL(transpose_split, gt, blk, 0, stream, Wq, Wth, Wtl, 0.125f);
    hipLaunchKernelGGL((gemm_split<1>), gg, blk, 0, stream,
                       xh, xl, Wth, Wtl, bq, 0.125f, nullptr, Qh_, Ql_);

    hipLaunchKernelGGL(transpose_split, gt, blk, 0, stream, Wk, Wth, Wtl, 1.0f);
    hipLaunchKernelGGL((gemm_split<1>), gg, blk, 0, stream,
                       xh, xl, Wth, Wtl, bk, 1.0f, nullptr, Kh_, Kl_);

    hipLaunchKernelGGL(transpose_split, gt, blk, 0, stream, Wv, Wth, Wtl, 1.0f);
    hipLaunchKernelGGL((gemm_split<2>), gg, blk, 0, stream,
                       xh, xl, Wth, Wtl, bv, 1.0f, nullptr, Vt_, nullptr);

    hipLaunchKernelGGL(attn_mfma2, dim3(NB * NUMH * 16), blk, 0, stream,
                       Qh_, Ql_, Kh_, Kl_, Vt_, xh, xl);   // ctx -> xh/xl

    hipLaunchKernelGGL(transpose_split, gt, blk, 0, stream, Wo, Wth, Wtl, 1.0f);
    hipLaunchKernelGGL((gemm_split<0>), gg, blk, 0, stream,
                       xh, xl, Wth, Wtl, bo, 1.0f, (float*)d_out, nullptr, nullptr);
}